// Round 9
// baseline (232.197 us; speedup 1.0000x reference)
//
#include <hip/hip_runtime.h>
#include <math.h>

#define BATCH  2
#define SEQ    2048
#define DMODEL 1024
#define NH     16
#define HD     64
#define NQKV   3072
#define ROWS   (BATCH*SEQ)
#define QSCALE 0.18033688f   // 0.125 * log2(e): QK^T scores land in log2 domain

typedef unsigned short u16;
typedef unsigned int   u32;
typedef __bf16 bf16x8 __attribute__((ext_vector_type(8)));
typedef float  f32x4  __attribute__((ext_vector_type(4)));

typedef const __attribute__((address_space(1))) void* gptr_t;
typedef __attribute__((address_space(3))) void* lptr_t;

__device__ __forceinline__ void gload16(lptr_t l, const void* g) {
    __builtin_amdgcn_global_load_lds((gptr_t)g, l, 16, 0, 0);
}

__device__ __forceinline__ u16 f2bf(float f) {          // RNE f32->bf16
    unsigned int u = __float_as_uint(f);
    u += 0x7FFFu + ((u >> 16) & 1u);
    return (u16)(u >> 16);
}
__device__ __forceinline__ u32 pk2(float lo, float hi) { // pack 2 f32 -> 2 bf16
#if __has_builtin(__builtin_amdgcn_cvt_pk_bf16_f32)
    typedef __bf16 bf16x2 __attribute__((ext_vector_type(2)));
    union { bf16x2 v; u32 u; } cv;
    cv.v = __builtin_amdgcn_cvt_pk_bf16_f32(lo, hi);
    return cv.u;
#else
    return (u32)f2bf(lo) | ((u32)f2bf(hi) << 16);
#endif
}
__device__ __forceinline__ float fexp2(float x) {
#if __has_builtin(__builtin_amdgcn_exp2f)
    return __builtin_amdgcn_exp2f(x);
#else
    return exp2f(x);
#endif
}

// ---------------------------------------------------------------------------
// fused prep: f32->bf16 for x/qkv_w/out_w, rope cos/sin table, bias wtab.
// ---------------------------------------------------------------------------
#define NBC ((ROWS*DMODEL + NQKV*DMODEL + DMODEL*DMODEL) / 1024)
__global__ void prep_kernel(const float* __restrict__ a,
                            const float* __restrict__ b,
                            const float* __restrict__ c,
                            u16* __restrict__ oa, u16* __restrict__ ob,
                            u16* __restrict__ oc,
                            const float* __restrict__ freqs, float* __restrict__ cs_tab,
                            const float* __restrict__ bias_p,
                            const float* __restrict__ bias_a,
                            float* __restrict__ wtab)
{
    const int na = ROWS*DMODEL, nb = NQKV*DMODEL;
    int blk = blockIdx.x;
    if (blk < NBC) {
        int i = (blk * 256 + threadIdx.x) * 4;
        const float* s; u16* d; int base;
        if (i < na)           { s = a; d = oa; base = i; }
        else if (i < na + nb) { s = b; d = ob; base = i - na; }
        else                  { s = c; d = oc; base = i - na - nb; }
        float4 v = *(const float4*)(s + base);
        u16 o[4] = { f2bf(v.x), f2bf(v.y), f2bf(v.z), f2bf(v.w) };
        *(uint2*)(d + base) = *(const uint2*)o;
    } else if (blk < NBC + 256) {
        int idx = (blk - NBC) * 256 + threadIdx.x;   // SEQ*32
        int s = idx >> 5, d = idx & 31;
        float sn, cs;
        sincosf((float)s * freqs[d], &sn, &cs);
        cs_tab[idx * 2]     = cs;
        cs_tab[idx * 2 + 1] = sn;
    } else {
        int idx = (blk - NBC - 256) * 256 + threadIdx.x;  // NH*SEQ
        int h = idx >> 11;
        int d = idx & (SEQ - 1);
        float p = fmaxf(bias_p[h], 0.01f);
        float aa = fmaxf(bias_a[h], 0.01f);
        wtab[idx] = __expf(-p * log1pf(aa * (float)d));
    }
}

// ---------------------------------------------------------------------------
// QKV GEMM, BK=64 (half the barriers of BK=32), fused RoPE + layout epilogue.
// LDS 32 KB; staging 8 gload16/wave/iter; frag swizzle chunk' = chunk^(row&7).
// ---------------------------------------------------------------------------
__global__ __launch_bounds__(256) void gemm_qkv(
    const u16* __restrict__ A, const u16* __restrict__ B,
    const float* __restrict__ cs_tab,
    u16* __restrict__ Qb, u16* __restrict__ Kb, u16* __restrict__ Vt)
{
    const int K = DMODEL;
    __shared__ __align__(16) u16 As[128*64];
    __shared__ __align__(16) u16 Bs[128*64];
    const int tid  = threadIdx.x;
    const int wave = tid >> 6, lane = tid & 63;
    const int quad = lane >> 4, l16 = lane & 15;
    const int wrow = (wave >> 1) * 64, wcol = (wave & 1) * 64;
    const int bm = blockIdx.x * 128, bn = blockIdx.y * 128;

    const int srow = lane >> 3;                       // 0..7
    const int scol = ((lane & 7) ^ srow) * 8;         // swizzled chunk (u16)
    const int fsw = l16 & 7;                          // frag row swizzle bits

    f32x4 acc[4][4];
#pragma unroll
    for (int i = 0; i < 4; ++i)
#pragma unroll
        for (int j = 0; j < 4; ++j) acc[i][j] = (f32x4){0.f,0.f,0.f,0.f};

    const u16* Ag[4]; const u16* Bg[4];
#pragma unroll
    for (int i = 0; i < 4; ++i) {
        Ag[i] = A + (size_t)(bm + wave*32 + i*8 + srow) * K + scol;
        Bg[i] = B + (size_t)(bn + wave*32 + i*8 + srow) * K + scol;
    }

    for (int k0 = 0; k0 < K; k0 += 64) {
        __syncthreads();
#pragma unroll
        for (int i = 0; i < 4; ++i) {
            gload16((lptr_t)&As[(wave*32 + i*8)*64], Ag[i] + k0);
            gload16((lptr_t)&Bs[(wave*32 + i*8)*64], Bg[i] + k0);
        }
        __syncthreads();
#pragma unroll
        for (int kk = 0; kk < 2; ++kk) {
            bf16x8 af[4], bfr[4];
#pragma unroll
            for (int i = 0; i < 4; ++i)
                af[i] = *(const bf16x8*)&As[(wrow + i*16 + l16)*64 + (((kk*4 + quad) ^ fsw) * 8)];
#pragma unroll
            for (int j = 0; j < 4; ++j)
                bfr[j] = *(const bf16x8*)&Bs[(wcol + j*16 + l16)*64 + (((kk*4 + quad) ^ fsw) * 8)];
#pragma unroll
            for (int i = 0; i < 4; ++i)
#pragma unroll
                for (int j = 0; j < 4; ++j)
                    acc[i][j] = __builtin_amdgcn_mfma_f32_16x16x32_bf16(af[i], bfr[j], acc[i][j], 0, 0, 0);
        }
    }

    // ---- fused epilogue (verified R6/R7/R8) ----
    const int tcol = (bn + wcol) >> 6;          // global 64-col index, 0..47
    const int t = tcol >> 4, h = tcol & 15;     // tensor (q/k/v), head
    const int bq = bm >> 11;                    // batch (tile never crosses)
    const int sb = (bm & (SEQ - 1)) + wrow;     // s base of this quadrant
    const size_t hb = (size_t)(bq * NH + h) * SEQ * HD;

    if (t == 2) {
#pragma unroll
        for (int i = 0; i < 4; ++i) {
            const int s = sb + i*16 + quad*4;
#pragma unroll
            for (int j = 0; j < 4; ++j) {
                const int d = j*16 + l16;
                uint2 pv = make_uint2(pk2(acc[i][j][0], acc[i][j][1]),
                                      pk2(acc[i][j][2], acc[i][j][3]));
                *(uint2*)&Vt[hb + (size_t)d * SEQ + s] = pv;
            }
        }
    } else {
        const float sc = (t == 0) ? QSCALE : 1.0f;
        u16* dstb = ((t == 0) ? Qb : Kb) + hb;
#pragma unroll
        for (int i = 0; i < 4; ++i) {
#pragma unroll
            for (int r = 0; r < 4; ++r) {
                const int s = sb + i*16 + quad*4 + r;
                const float2* ct = (const float2*)(cs_tab + ((size_t)s * 32 + l16) * 2);
                float2 cs0 = ct[0];     // freq idx l16
                float2 cs1 = ct[16];    // freq idx l16+16
                float a0 = acc[i][0][r], a1 = acc[i][1][r];
                float a2 = acc[i][2][r], a3 = acc[i][3][r];
                u16* dst = dstb + (size_t)s * HD;
                dst[l16]      = f2bf((a0*cs0.x - a2*cs0.y) * sc);
                dst[16 + l16] = f2bf((a1*cs1.x - a3*cs1.y) * sc);
                dst[32 + l16] = f2bf((a0*cs0.y + a2*cs0.x) * sc);
                dst[48 + l16] = f2bf((a1*cs1.y + a3*cs1.x) * sc);
            }
        }
    }
}

// ---------------------------------------------------------------------------
// out-projection GEMM: 128x64 tile -> 512 blocks = 2+/CU (verified R8).
// ---------------------------------------------------------------------------
__global__ __launch_bounds__(256) void gemm_out(
    const u16* __restrict__ A, const u16* __restrict__ B,
    float* __restrict__ Cout, int M, int N, int K)
{
    __shared__ __align__(16) u16 As[128][32];
    __shared__ __align__(16) u16 Bs[64][32];
    const int tid  = threadIdx.x;
    const int wave = tid >> 6, lane = tid & 63;
    const int quad = lane >> 4, l16 = lane & 15;
    const int wrow = (wave >> 1) * 64, wcol = (wave & 1) * 32;
    const int bm = blockIdx.x * 128, bn = blockIdx.y * 64;

    const int srow = lane >> 2;
    const int scol = ((lane & 3) ^ (srow & 3)) * 8;
    const int fsw = (quad ^ (l16 & 3)) * 8;

    f32x4 acc[4][2];
#pragma unroll
    for (int i = 0; i < 4; ++i)
#pragma unroll
        for (int j = 0; j < 2; ++j) acc[i][j] = (f32x4){0.f,0.f,0.f,0.f};

    const u16* Ag0 = A + (size_t)(bm + wave*32 + srow)      * K + scol;
    const u16* Ag1 = A + (size_t)(bm + wave*32 + 16 + srow) * K + scol;
    const u16* Bg0 = B + (size_t)(bn + wave*16 + srow)      * K + scol;

    for (int k0 = 0; k0 < K; k0 += 32) {
        __syncthreads();
        gload16((lptr_t)&As[wave*32][0],      Ag0 + k0);
        gload16((lptr_t)&As[wave*32 + 16][0], Ag1 + k0);
        gload16((lptr_t)&Bs[wave*16][0],      Bg0 + k0);
        __syncthreads();
        bf16x8 af[4], bfr[2];
#pragma unroll
        for (int i = 0; i < 4; ++i)
            af[i] = *(const bf16x8*)&As[wrow + i*16 + l16][fsw];
#pragma unroll
        for (int j = 0; j < 2; ++j)
            bfr[j] = *(const bf16x8*)&Bs[wcol + j*16 + l16][fsw];
#pragma unroll
        for (int i = 0; i < 4; ++i)
#pragma unroll
            for (int j = 0; j < 2; ++j)
                acc[i][j] = __builtin_amdgcn_mfma_f32_16x16x32_bf16(af[i], bfr[j], acc[i][j], 0, 0, 0);
    }

#pragma unroll
    for (int i = 0; i < 4; ++i)
#pragma unroll
        for (int j = 0; j < 2; ++j) {
            int col = bn + wcol + j*16 + l16;
#pragma unroll
            for (int r = 0; r < 4; ++r) {
                int row = bm + wrow + i*16 + quad*4 + r;
                Cout[(size_t)row * N + col] = acc[i][j][r];
            }
        }
}

// ---------------------------------------------------------------------------
// MFMA flash attention (R5/R7, measured 79.5 us): 64-key tiles, gload16-staged
// K/V, swapped scores S^T = K*Q^T, packed P writes, multiplicative bias window.
// ---------------------------------------------------------------------------
__global__ __launch_bounds__(256) void attn_mfma(
    const u16* __restrict__ Qb, const u16* __restrict__ Kb,
    const u16* __restrict__ Vt, const float* __restrict__ wtab,
    u16* __restrict__ attn_bf)
{
    __shared__ __align__(16) u16 Ks[64*64];    // [key][d], chunk-swizzled
    __shared__ __align__(16) u16 Vs[64*64];    // [d][key], chunk-swizzled
    __shared__ __align__(16) u16 Ps[64][72];   // [q][key], padded
    __shared__ u32 ws2[128];                   // packed {w[m], w[m+1]}
    __shared__ float lred[4][64];
    __shared__ float linv[64];

    const int tid = threadIdx.x;
    const int wave = tid >> 6, lane = tid & 63;
    const int quad = lane >> 4, l16 = lane & 15;
    const int q0 = blockIdx.x * 64, h = blockIdx.y, b = blockIdx.z;

    const u16* Qh = Qb + (size_t)(b * NH + h) * SEQ * HD;
    const u16* Kh = Kb + (size_t)(b * NH + h) * SEQ * HD;
    const u16* Vh = Vt + (size_t)(b * NH + h) * HD * SEQ;
    const float* wh = wtab + h * SEQ;

    bf16x8 qf0[4], qf1[4];
#pragma unroll
    for (int qj = 0; qj < 4; ++qj) {
        const u16* qr = Qh + (size_t)(q0 + qj*16 + l16) * HD + quad * 8;
        qf0[qj] = *(const bf16x8*)qr;
        qf1[qj] = *(const bf16x8*)(qr + 32);
    }

    const int srow = lane >> 3;
    const int scol = ((lane & 7) ^ srow) * 8;
    const u16* Kg0 = Kh + (size_t)(wave*16 + srow)     * HD + scol;
    const u16* Kg1 = Kh + (size_t)(wave*16 + 8 + srow) * HD + scol;
    const u16* Vg0 = Vh + (size_t)(wave*16 + srow)     * SEQ + scol;
    const u16* Vg1 = Vh + (size_t)(wave*16 + 8 + srow) * SEQ + scol;

    const int sw  = (quad ^ (l16 & 7)) * 8;
    const int mb0 = 63 + l16 - wave*16 - quad*4 - 3;

    float l_p[4] = {0.f, 0.f, 0.f, 0.f};
    f32x4 o[4];
#pragma unroll
    for (int j = 0; j < 4; ++j) o[j] = (f32x4){0.f,0.f,0.f,0.f};

    for (int kt = 0; kt < SEQ / 64; ++kt) {
        const int k0 = kt * 64;
        __syncthreads();
        gload16((lptr_t)&Ks[(wave*16)*64],     Kg0 + (size_t)k0 * HD);
        gload16((lptr_t)&Ks[(wave*16 + 8)*64], Kg1 + (size_t)k0 * HD);
        gload16((lptr_t)&Vs[(wave*16)*64],     Vg0 + k0);
        gload16((lptr_t)&Vs[(wave*16 + 8)*64], Vg1 + k0);
        if (tid < 128) {
            int i0 = (q0 - k0 - 63) + tid;
            int a0 = i0 < 0 ? -i0 : i0;  if (a0 > SEQ-1) a0 = SEQ-1;
            int i1 = i0 + 1;
            int a1 = i1 < 0 ? -i1 : i1;  if (a1 > SEQ-1) a1 = SEQ-1;
            ws2[tid] = pk2(wh[a0], wh[a1]);
        }
        __syncthreads();

        bf16x8 kf0 = *(const bf16x8*)&Ks[(wave*16 + l16)*64 + sw];
        bf16x8 kf1 = *(const bf16x8*)&Ks[(wave*16 + l16)*64 + (sw ^ 32)];
#pragma unroll
        for (int qj = 0; qj < 4; ++qj) {
            f32x4 z = (f32x4){0.f,0.f,0.f,0.f};
            z = __builtin_amdgcn_mfma_f32_16x16x32_bf16(kf0, qf0[qj], z, 0, 0, 0);
            z = __builtin_amdgcn_mfma_f32_16x16x32_bf16(kf1, qf1[qj], z, 0, 0, 0);
            const int mbase = mb0 + qj*16;
            u32 pA = ws2[mbase], pB = ws2[mbase + 2];
            float w3 = __uint_as_float(pA << 16);
            float w2 = __uint_as_float(pA & 0xffff0000u);
            float w1 = __uint_as_float(pB << 16);
            float w0 = __uint_as_float(pB & 0xffff0000u);
            float e0 = fexp2(z[0]) * w0, e1 = fexp2(z[1]) * w1;
            float e2 = fexp2(z[2]) * w2, e3 = fexp2(z[3]) * w3;
            l_p[qj] += (e0 + e1) + (e2 + e3);
            *(uint2*)&Ps[qj*16 + l16][wave*16 + quad*4] =
                make_uint2(pk2(e0, e1), pk2(e2, e3));
        }
        __syncthreads();

        bf16x8 pf0 = *(const bf16x8*)&Ps[wave*16 + l16][quad*8];
        bf16x8 pf1 = *(const bf16x8*)&Ps[wave*16 + l16][32 + quad*8];
#pragma unroll
        for (int j = 0; j < 4; ++j) {
            bf16x8 vf0 = *(const bf16x8*)&Vs[(j*16 + l16)*64 + sw];
            bf16x8 vf1 = *(const bf16x8*)&Vs[(j*16 + l16)*64 + (sw ^ 32)];
            o[j] = __builtin_amdgcn_mfma_f32_16x16x32_bf16(pf0, vf0, o[j], 0, 0, 0);
            o[j] = __builtin_amdgcn_mfma_f32_16x16x32_bf16(pf1, vf1, o[j], 0, 0, 0);
        }
    }

#pragma unroll
    for (int qj = 0; qj < 4; ++qj) {
        float l = l_p[qj];
        l += __shfl_xor(l, 16);
        l += __shfl_xor(l, 32);
        if (quad == 0) lred[wave][qj*16 + l16] = l;
    }
    __syncthreads();
    if (tid < 64)
        linv[tid] = 1.0f / (lred[0][tid] + lred[1][tid] + lred[2][tid] + lred[3][tid]);
    __syncthreads();
#pragma unroll
    for (int r = 0; r < 4; ++r) {
        const int q = wave*16 + quad*4 + r;
        float inv = linv[q];
        u16* dst = attn_bf + (size_t)(b * SEQ + q0 + q) * DMODEL + h * HD;
#pragma unroll
        for (int j = 0; j < 4; ++j)
            dst[j*16 + l16] = f2bf(o[j][r] * inv);
    }
}

// ---------------------------------------------------------------------------
extern "C" void kernel_launch(void* const* d_in, const int* in_sizes, int n_in,
                              void* d_out, int out_size, void* d_ws, size_t ws_size,
                              hipStream_t stream)
{
    (void)in_sizes; (void)n_in; (void)out_size; (void)ws_size;
    const float* x      = (const float*)d_in[0];
    const float* qkv_w  = (const float*)d_in[1];
    const float* out_w  = (const float*)d_in[2];
    const float* bias_p = (const float*)d_in[3];
    const float* bias_a = (const float*)d_in[4];
    const float* freqs  = (const float*)d_in[5];
    float* out = (float*)d_out;

    char* ws = (char*)d_ws;
    u16*   attn_bf = (u16*)ws;
    u16*   Qb      = (u16*)(ws + 8388608);
    u16*   x_bf    = (u16*)(ws + 25165824);
    u16*   w1_bf   = (u16*)(ws + 33554432);
    u16*   w2_bf   = (u16*)(ws + 39845888);
    u16*   Kb      = (u16*)(ws + 41943040);
    u16*   Vt      = (u16*)(ws + 50331648);
    float* wtab    = (float*)(ws + 58720256);
    float* cs_tab  = (float*)(ws + 58720256 + 131072);

    prep_kernel<<<dim3(NBC + 256 + 128), 256, 0, stream>>>(
        x, qkv_w, out_w, x_bf, w1_bf, w2_bf, freqs, cs_tab, bias_p, bias_a, wtab);

    gemm_qkv<<<dim3(ROWS/128, NQKV/128), 256, 0, stream>>>(x_bf, w1_bf, cs_tab, Qb, Kb, Vt);
    attn_mfma<<<dim3(SEQ/64, NH, BATCH), 256, 0, stream>>>(Qb, Kb, Vt, wtab, attn_bf);
    gemm_out<<<dim3(ROWS/128, DMODEL/64), 256, 0, stream>>>(attn_bf, w2_bf, out, ROWS, DMODEL, DMODEL);
}